// Round 14
// baseline (12790.965 us; speedup 1.0000x reference)
//
#include <hip/hip_runtime.h>
#include <cstdint>
#include <cstddef>

typedef _Float16 f16;
typedef _Float16 f16x8 __attribute__((ext_vector_type(8)));
typedef float f32x4 __attribute__((ext_vector_type(4)));
typedef unsigned long long u64;

#define T_LEN 1200
#define NB 32
#define HD 384

__device__ __forceinline__ float sigf(float x) { return 1.f / (1.f + __expf(-x)); }
__device__ __forceinline__ float tanhf_s(float x) {
    float ax = fabsf(x);
    float e = __expf(-2.f * ax);
    float r = (1.f - e) / (1.f + e);
    return copysignf(r, x);
}
__device__ __forceinline__ float siluf(float x) { return x * sigf(x); }

// Device-visible 8B single-copy-atomic packet {h, tag} (r6-proven wire).
__device__ __forceinline__ u64 ld_pkt_sys(const u64* p) {
    u64 r;
    asm volatile("global_load_dwordx2 %0, %1, off sc0 sc1\n\ts_waitcnt vmcnt(0)"
                 : "=v"(r) : "v"(p) : "memory");
    return r;
}
__device__ __forceinline__ void st_pkt_sys(u64* p, u64 v) {
    asm volatile("global_store_dwordx2 %0, %1, off sc0 sc1" :: "v"(p), "v"(v) : "memory");
}

// ---------------- small conversion kernels ----------------
__global__ void k_cvt(const float* __restrict__ src, f16* __restrict__ dst, int n) {
    int i = blockIdx.x * 256 + threadIdx.x;
    if (i < n) dst[i] = (f16)src[i];
}

__global__ void k_w3p(const float* __restrict__ w3, f16* __restrict__ dst) {
    int i = blockIdx.x * 256 + threadIdx.x; // 384*320
    if (i >= 384 * 320) return;
    int c = i / 320, k = i % 320;
    dst[i] = (f16)((k < 304) ? w3[c * 304 + k] : 0.f);
}

// ---------------- conv1 + conv2 fused (f32 out) ----------------
__global__ __launch_bounds__(512) void k_conv12(const float* __restrict__ x,
    const float* __restrict__ w1, const float* __restrict__ b1,
    const float* __restrict__ w2, const float* __restrict__ b2,
    float* __restrict__ c2) {
    const int tid = threadIdx.x;
    const int n = blockIdx.y;
    const int t0 = blockIdx.x * 512;
    __shared__ float xs[520];
    __shared__ float c1s[4][520];
    __shared__ float ws1[20], wb1[4], ws2[320], wb2[16];
    if (tid < 20) ws1[tid] = w1[tid];
    if (tid < 4) wb1[tid] = b1[tid];
    if (tid < 320) ws2[tid] = w2[tid];
    if (tid < 16) wb2[tid] = b2[tid];
    for (int q = tid; q < 520; q += 512) {
        int xi = t0 - 4 + q;
        xs[q] = (xi >= 0 && xi < 6000) ? x[(size_t)n * 6000 + xi] : 0.f;
    }
    __syncthreads();
    for (int p = tid; p < 516; p += 512) {
        int gp = t0 - 2 + p;
#pragma unroll
        for (int ch = 0; ch < 4; ++ch) {
            float a = wb1[ch];
#pragma unroll
            for (int j = 0; j < 5; ++j) a += ws1[ch * 5 + j] * xs[p + j];
            c1s[ch][p] = (gp >= 0 && gp < 6000) ? siluf(a) : 0.f;
        }
    }
    __syncthreads();
    int pos = t0 + tid;
    if (pos < 6000) {
#pragma unroll
        for (int oc = 0; oc < 16; ++oc) {
            float a = wb2[oc];
#pragma unroll
            for (int ic = 0; ic < 4; ++ic)
#pragma unroll
                for (int j = 0; j < 5; ++j)
                    a += ws2[(oc * 4 + ic) * 5 + j] * c1s[ic][tid + j];
            c2[((size_t)n * 16 + oc) * 6000 + pos] = siluf(a);
        }
    }
}

// ---------------- im2col for conv3 (K padded 304 -> 320) ----------------
__global__ void k_im2col(const float* __restrict__ c2, float* __restrict__ A3) {
    int flat = blockIdx.x * 256 + threadIdx.x; // < 38400*40
    int m = flat / 40, c8 = flat % 40;
    int t = m >> 5, n = m & 31;
    float v[8];
#pragma unroll
    for (int e = 0; e < 8; ++e) {
        int k = c8 * 8 + e;
        float r = 0.f;
        if (k < 304) {
            int ic = k / 19, j = k % 19;
            int p = t * 5 - 9 + j;
            if (p >= 0 && p < 6000) r = c2[((size_t)n * 16 + ic) * 6000 + p];
        }
        v[e] = r;
    }
    float4 a, b;
    a.x = v[0]; a.y = v[1]; a.z = v[2]; a.w = v[3];
    b.x = v[4]; b.y = v[5]; b.z = v[6]; b.w = v[7];
    *(float4*)&A3[(size_t)m * 320 + c8 * 8] = a;
    *(float4*)&A3[(size_t)m * 320 + c8 * 8 + 4] = b;
}

// ---------------- MFMA GEMM: C[M,N] = act(A[M,K] @ B[N,K]^T + bias) ----------------
template <int ACT, typename OT>
__global__ __launch_bounds__(256, 2) void k_gemm(const float* __restrict__ A, const f16* __restrict__ B,
    const float* __restrict__ bias, OT* __restrict__ C, int K, int N) {
    const int tid = threadIdx.x;
    const int lane = tid & 63, wv = tid >> 6;
    const int wm = wv >> 1, wn = wv & 1;
    const int m0 = blockIdx.x * 128, n0 = blockIdx.y * 128;
    __shared__ __align__(16) f16 As[128 * 64];
    __shared__ __align__(16) f16 Al[128 * 64];
    __shared__ __align__(16) f16 Bs[128 * 64];
    f32x4 acc[4][4] = {};
    const int nk = K >> 6;
    for (int kb = 0; kb < nk; ++kb) {
#pragma unroll
        for (int i = 0; i < 4; ++i) {
            int cf = tid + i * 256;
            int row = cf >> 3, c = cf & 7;
            int sw = ((c ^ (row & 7)) << 3);
            *(f16x8*)&Bs[row * 64 + sw] = *(const f16x8*)&B[(size_t)(n0 + row) * K + kb * 64 + c * 8];
            float4 v0 = *(const float4*)&A[(size_t)(m0 + row) * K + kb * 64 + c * 8];
            float4 v1 = *(const float4*)&A[(size_t)(m0 + row) * K + kb * 64 + c * 8 + 4];
            float vv[8] = {v0.x, v0.y, v0.z, v0.w, v1.x, v1.y, v1.z, v1.w};
            f16x8 hi, lo;
#pragma unroll
            for (int e = 0; e < 8; ++e) {
                f16 h = (f16)vv[e];
                hi[e] = h;
                lo[e] = (f16)(vv[e] - (float)h);
            }
            *(f16x8*)&As[row * 64 + sw] = hi;
            *(f16x8*)&Al[row * 64 + sw] = lo;
        }
        __syncthreads();
#pragma unroll
        for (int kk = 0; kk < 2; ++kk) {
            f16x8 afh[4], afl[4], bf[4];
#pragma unroll
            for (int mi = 0; mi < 4; ++mi) {
                int row = wm * 64 + mi * 16 + (lane & 15);
                int c = kk * 4 + (lane >> 4);
                afh[mi] = *(const f16x8*)&As[row * 64 + ((c ^ (row & 7)) << 3)];
                afl[mi] = *(const f16x8*)&Al[row * 64 + ((c ^ (row & 7)) << 3)];
            }
#pragma unroll
            for (int ni = 0; ni < 4; ++ni) {
                int row = wn * 64 + ni * 16 + (lane & 15);
                int c = kk * 4 + (lane >> 4);
                bf[ni] = *(const f16x8*)&Bs[row * 64 + ((c ^ (row & 7)) << 3)];
            }
#pragma unroll
            for (int mi = 0; mi < 4; ++mi)
#pragma unroll
                for (int ni = 0; ni < 4; ++ni) {
                    acc[mi][ni] = __builtin_amdgcn_mfma_f32_16x16x32_f16(afh[mi], bf[ni], acc[mi][ni], 0, 0, 0);
                    acc[mi][ni] = __builtin_amdgcn_mfma_f32_16x16x32_f16(afl[mi], bf[ni], acc[mi][ni], 0, 0, 0);
                }
        }
        __syncthreads();
    }
#pragma unroll
    for (int mi = 0; mi < 4; ++mi) {
#pragma unroll
        for (int ni = 0; ni < 4; ++ni) {
            int gcol = n0 + wn * 64 + ni * 16 + (lane & 15);
            float bv = bias[gcol];
#pragma unroll
            for (int r = 0; r < 4; ++r) {
                int grow = m0 + wm * 64 + mi * 16 + (lane >> 4) * 4 + r;
                float v = acc[mi][ni][r] + bv;
                if (ACT == 1) v = v * (1.f / (1.f + __expf(-v)));
                else if (ACT == 2) v = 5.f - 10.f / (__expf(2.f * v) + 1.f);
                C[(size_t)grow * N + gcol] = (OT)v;
            }
        }
    }
}

// ---------------- LSTM recurrence: 32 teams (samples) x 8 WGs x 512 thr ----------------
// r12 structure. New in r14: SPIN THROTTLING. 86K device-wide pollers in tight
// blocking-load loops were congesting the L3 coherence point (O(20 TB/s) of
// 64B-line traffic), inflating the packet RT several-fold. Consumers (waves
// 1-6; producers are wave 0, unaffected by wave-level s_sleep) now sleep
// ~640cyc before the first poll (matching producer gate+store latency) and
// ~128cyc between retries -> poll traffic drops 10-20x, RT decongests.
__global__ __launch_bounds__(512, 2) void k_rec(const float* __restrict__ G,
    const float* __restrict__ whh, float* __restrict__ Xout,
    u64* __restrict__ tup, int rev, unsigned tagbase) {
    const int tid = threadIdx.x;
    const int n = blockIdx.x & 31, w = blockIdx.x >> 5;
    const int g3 = tid >> 3, kq = tid & 7;
    __shared__ __align__(16) float hlds[416]; // 8 chunks x 52 (48 used): kq start
    __shared__ float gbuf[192];               // banks {0,20,8,28,16,4,24,12} - conflict-free
    float4 wreg[3][12];
#pragma unroll
    for (int r = 0; r < 3; ++r) {
        int lr = 3 * g3 + r;             // 0..191
        int gate = lr / 48, unit = lr % 48;
        const float* wp = whh + (size_t)(gate * HD + w * 48 + unit) * HD + kq * 48;
#pragma unroll
        for (int q = 0; q < 12; ++q) wreg[r][q] = *(const float4*)(wp + 4 * q);
    }
    if (tid < 416) hlds[tid] = 0.f;
    float cst = 0.f;
    // poller setup: absolute unit uu of a remote WG
    const bool isP = (tid >= 64 && tid < 400);
    int uu = 0; float* hq = nullptr;
    if (isP) {
        int p = tid - 64;                 // 0..335
        uu = (p < w * 48) ? p : (p + 48); // skip own WG's 48 units
        hq = &hlds[(uu / 48) * 52 + (uu % 48)];
    }
    float pg0 = 0.f, pg1 = 0.f, pg2 = 0.f, pg3 = 0.f;
    if (tid < 48) {
        int t0 = rev ? (T_LEN - 1) : 0;
        size_t gb = ((size_t)t0 * NB + n) * 1536 + w * 48 + tid;
        pg0 = G[gb]; pg1 = G[gb + 384]; pg2 = G[gb + 768]; pg3 = G[gb + 1152];
    }
    __syncthreads();

    for (int s = 0; s < T_LEN; ++s) {
        float q0 = 0.f, q1 = 0.f, q2 = 0.f, q3 = 0.f;
        const bool pref = (tid < 48) && (s + 1 < T_LEN);
        if (pref) {
            int tn = rev ? (T_LEN - 2 - s) : (s + 1);
            size_t gb = ((size_t)tn * NB + n) * 1536 + w * 48 + tid;
            q0 = G[gb]; q1 = G[gb + 384]; q2 = G[gb + 768]; q3 = G[gb + 1152];
        }
        // ---- matvec: 3 rows x 48 cols per thread, weights in VGPRs ----
        float a0 = 0.f, a1 = 0.f, a2 = 0.f;
        const float4* hp = (const float4*)&hlds[kq * 52];
#pragma unroll
        for (int q = 0; q < 12; ++q) {
            float4 hv = hp[q];
            a0 = fmaf(wreg[0][q].x, hv.x, a0); a0 = fmaf(wreg[0][q].y, hv.y, a0);
            a0 = fmaf(wreg[0][q].z, hv.z, a0); a0 = fmaf(wreg[0][q].w, hv.w, a0);
            a1 = fmaf(wreg[1][q].x, hv.x, a1); a1 = fmaf(wreg[1][q].y, hv.y, a1);
            a1 = fmaf(wreg[1][q].z, hv.z, a1); a1 = fmaf(wreg[1][q].w, hv.w, a1);
            a2 = fmaf(wreg[2][q].x, hv.x, a2); a2 = fmaf(wreg[2][q].y, hv.y, a2);
            a2 = fmaf(wreg[2][q].z, hv.z, a2); a2 = fmaf(wreg[2][q].w, hv.w, a2);
        }
        a0 += __shfl_xor(a0, 1); a0 += __shfl_xor(a0, 2); a0 += __shfl_xor(a0, 4);
        a1 += __shfl_xor(a1, 1); a1 += __shfl_xor(a1, 2); a1 += __shfl_xor(a1, 4);
        a2 += __shfl_xor(a2, 1); a2 += __shfl_xor(a2, 2); a2 += __shfl_xor(a2, 4);
        if (kq == 0) {
            gbuf[3 * g3 + 0] = a0;
            gbuf[3 * g3 + 1] = a1;
            gbuf[3 * g3 + 2] = a2;
        }
        if (pref) {
            asm volatile("" : "+v"(q0), "+v"(q1), "+v"(q2), "+v"(q3));
        }
        __syncthreads(); // B1: gbuf ready; all hlds reads of step s done
        const int slot = s & 1;
        const unsigned tag = tagbase + (unsigned)s + 1u;
        if (tid < 48) {
            float iv = pg0 + gbuf[tid];
            float fv = pg1 + gbuf[48 + tid];
            float gv = pg2 + gbuf[96 + tid];
            float ov = pg3 + gbuf[144 + tid];
            cst = sigf(fv) * cst + sigf(iv) * tanhf_s(gv);
            float hv = sigf(ov) * tanhf_s(cst);
            int t = rev ? (T_LEN - 1 - s) : s;
            Xout[((size_t)t * NB + n) * HD + w * 48 + tid] = hv;
            hlds[w * 52 + tid] = hv; // own-WG hlds direct
            if (s + 1 < T_LEN)
                st_pkt_sys(&tup[((size_t)slot * NB + n) * 384 + w * 48 + tid],
                           ((u64)tag << 32) | (u64)__builtin_bit_cast(unsigned, hv));
        } else if (isP && s + 1 < T_LEN) {
            // throttled poll: sleep past producer gate+store latency, then
            // low-rate retries. Sleeps are wave-level; producers are wave 0.
            __builtin_amdgcn_s_sleep(10); // ~640 cyc
            const u64* ta = &tup[((size_t)slot * NB + n) * 384 + uu];
            u64 v = ld_pkt_sys(ta);
            int it = 0;
            while ((unsigned)(v >> 32) != tag && ++it < 500000) {
                __builtin_amdgcn_s_sleep(2); // ~128 cyc between retries
                v = ld_pkt_sys(ta);
            }
            hq[0] = __builtin_bit_cast(float, (unsigned)v);
        }
        if (pref) { pg0 = q0; pg1 = q1; pg2 = q2; pg3 = q3; }
        __syncthreads(); // B2: hlds for step s+1 complete
    }
}

// ---------------- CRF logZ ----------------
__global__ __launch_bounds__(256) void k_crf(const float* __restrict__ S,
    const int* __restrict__ idx, float* __restrict__ logz) {
    const int n = blockIdx.x, s = threadIdx.x;
    __shared__ float ash[256];
    __shared__ float bsh[256];
    int ix[5];
#pragma unroll
    for (int a = 0; a < 5; ++a) ix[a] = idx[s * 5 + a];
    float alpha = 0.f;
    float M[5];
#pragma unroll
    for (int a = 0; a < 5; ++a) M[a] = S[(size_t)n * 1280 + s * 5 + a];
    for (int t = 0; t < T_LEN; ++t) {
        ash[s] = alpha;
        __syncthreads();
        float av[5];
#pragma unroll
        for (int a = 0; a < 5; ++a) av[a] = ash[ix[a]] + M[a];
        if (t + 1 < T_LEN) {
#pragma unroll
            for (int a = 0; a < 5; ++a) M[a] = S[((size_t)(t + 1) * NB + n) * 1280 + s * 5 + a];
        }
        float mx = av[0];
#pragma unroll
        for (int a = 1; a < 5; ++a) mx = fmaxf(mx, av[a]);
        float sum = 0.f;
#pragma unroll
        for (int a = 0; a < 5; ++a) sum += __expf(av[a] - mx);
        alpha = mx + __logf(sum);
        __syncthreads();
    }
    ash[s] = alpha;
    __syncthreads();
    for (int off = 128; off > 0; off >>= 1) {
        if (s < off) ash[s] = fmaxf(ash[s], ash[s + off]);
        __syncthreads();
    }
    float mxv = ash[0];
    bsh[s] = __expf(alpha - mxv);
    __syncthreads();
    for (int off = 128; off > 0; off >>= 1) {
        if (s < off) bsh[s] += bsh[s + off];
        __syncthreads();
    }
    if (s == 0) logz[n] = mxv + __logf(bsh[0]);
}

// ---------------- subtract logz/T ----------------
__global__ void k_sub(float* __restrict__ out, const float* __restrict__ logz) {
    size_t i = (size_t)blockIdx.x * 256 + threadIdx.x; // one float4 each
    float4* p = (float4*)out + i;
    int nn = (int)((i / 320) & 31);
    float d = logz[nn] * (1.f / 1200.f);
    float4 v = *p;
    v.x -= d; v.y -= d; v.z -= d; v.w -= d;
    *p = v;
}

extern "C" void kernel_launch(void* const* d_in, const int* in_sizes, int n_in,
                              void* d_out, int out_size, void* d_ws, size_t ws_size,
                              hipStream_t stream) {
    (void)in_sizes; (void)n_in; (void)out_size; (void)ws_size;
    const float* x    = (const float*)d_in[0];
    const float* w1   = (const float*)d_in[1];
    const float* b1   = (const float*)d_in[2];
    const float* w2   = (const float*)d_in[3];
    const float* b2   = (const float*)d_in[4];
    const float* w3   = (const float*)d_in[5];
    const float* b3   = (const float*)d_in[6];
    const float* linw = (const float*)d_in[7];
    const float* linb = (const float*)d_in[8];
    const float* wih[5];
    const float* whh[5];
    const float* lb[5];
    for (int l = 0; l < 5; ++l) {
        wih[l] = (const float*)d_in[9 + 3 * l];
        whh[l] = (const float*)d_in[10 + 3 * l];
        lb[l]  = (const float*)d_in[11 + 3 * l];
    }
    const int* idx = (const int*)d_in[24];
    float* out = (float*)d_out;
    char* ws = (char*)d_ws;

    float* G32   = (float*)(ws + 0);            // 235,929,600
    float* A3f   = (float*)(ws + 0);            // 49,152,000 (overlaps G, used before)
    float* c2f   = (float*)(ws + 56000000);     // 12,288,000 (overlaps G, used before)
    float* Xa32  = (float*)(ws + 235929600);    // 58,982,400
    float* Xb32  = (float*)(ws + 294912000);    // 58,982,400
    f16* wihf    = (f16*)(ws + 353894400);      // 5,898,240
    f16* linwf   = (f16*)(ws + 359792640);      // 983,040
    f16* w3p     = (f16*)(ws + 360775680);      // 245,760 (dead after conv3 GEMM)
    float* logz  = (float*)(ws + 361021440);    // 128

    for (int l = 0; l < 5; ++l)
        k_cvt<<<dim3(2304), 256, 0, stream>>>(wih[l], wihf + (size_t)l * 589824, 589824);
    k_cvt<<<dim3(1920), 256, 0, stream>>>(linw, linwf, 491520);
    k_w3p<<<dim3(480), 256, 0, stream>>>(w3, w3p);
    k_conv12<<<dim3(12, 32), 512, 0, stream>>>(x, w1, b1, w2, b2, c2f);
    k_im2col<<<dim3(6000), 256, 0, stream>>>(c2f, A3f);
    k_gemm<1, float><<<dim3(300, 3), 256, 0, stream>>>(A3f, w3p, b3, Xa32, 320, 384);

    // Packet buffer lives in the head of the CURRENT layer's input X buffer
    // (fully dead once k_gemm<0> consumed it; alternates with the output
    // buffer). Stale same-tag packets across graph replays are bit-identical
    // by determinism; X-data leftovers cannot collide with tag values (small
    // ints = denormal bit patterns, unreachable under FTZ). [r10-r13 validated]
    float* Xcur = Xa32;
    float* Xnxt = Xb32;
    for (int l = 0; l < 5; ++l) {
        k_gemm<0, float><<<dim3(300, 12), 256, 0, stream>>>(Xcur, wihf + (size_t)l * 589824, lb[l], G32, 384, 1536);
        u64* tup = (u64*)Xcur; // 2 slots x 32 x 384 x 8B = 196,608 B
        k_rec<<<dim3(256), 512, 0, stream>>>(G32, whh[l], Xnxt, tup,
                                             ((l & 1) == 0) ? 1 : 0, (unsigned)(l * 4096 + 1));
        float* tmp = Xcur; Xcur = Xnxt; Xnxt = tmp;
    }
    k_gemm<2, float><<<dim3(300, 10), 256, 0, stream>>>(Xcur, linwf, linb, out, 384, 1280);
    k_crf<<<dim3(32), 256, 0, stream>>>(out, idx, logz);
    k_sub<<<dim3(48000), 256, 0, stream>>>(out, logz);
}

// Round 17
// 11826.228 us; speedup vs baseline: 1.0816x; 1.0816x over previous
//
#include <hip/hip_runtime.h>
#include <cstdint>
#include <cstddef>

typedef _Float16 f16;
typedef _Float16 f16x8 __attribute__((ext_vector_type(8)));
typedef float f32x4 __attribute__((ext_vector_type(4)));
typedef unsigned long long u64;

#define T_LEN 1200
#define NB 32
#define HD 384

__device__ __forceinline__ float sigf(float x) { return 1.f / (1.f + __expf(-x)); }
__device__ __forceinline__ float tanhf_s(float x) {
    float ax = fabsf(x);
    float e = __expf(-2.f * ax);
    float r = (1.f - e) / (1.f + e);
    return copysignf(r, x);
}
__device__ __forceinline__ float siluf(float x) { return x * sigf(x); }

// Device-visible 8B single-copy-atomic packet {h, tag} (r6-proven wire).
__device__ __forceinline__ u64 ld_pkt_sys(const u64* p) {
    u64 r;
    asm volatile("global_load_dwordx2 %0, %1, off sc0 sc1\n\ts_waitcnt vmcnt(0)"
                 : "=v"(r) : "v"(p) : "memory");
    return r;
}
__device__ __forceinline__ void st_pkt_sys(u64* p, u64 v) {
    asm volatile("global_store_dwordx2 %0, %1, off sc0 sc1" :: "v"(p), "v"(v) : "memory");
}

// ---------------- small conversion kernels ----------------
__global__ void k_cvt(const float* __restrict__ src, f16* __restrict__ dst, int n) {
    int i = blockIdx.x * 256 + threadIdx.x;
    if (i < n) dst[i] = (f16)src[i];
}

__global__ void k_w3p(const float* __restrict__ w3, f16* __restrict__ dst) {
    int i = blockIdx.x * 256 + threadIdx.x; // 384*320
    if (i >= 384 * 320) return;
    int c = i / 320, k = i % 320;
    dst[i] = (f16)((k < 304) ? w3[c * 304 + k] : 0.f);
}

// ---------------- conv1 + conv2 fused (f32 out) ----------------
__global__ __launch_bounds__(512) void k_conv12(const float* __restrict__ x,
    const float* __restrict__ w1, const float* __restrict__ b1,
    const float* __restrict__ w2, const float* __restrict__ b2,
    float* __restrict__ c2) {
    const int tid = threadIdx.x;
    const int n = blockIdx.y;
    const int t0 = blockIdx.x * 512;
    __shared__ float xs[520];
    __shared__ float c1s[4][520];
    __shared__ float ws1[20], wb1[4], ws2[320], wb2[16];
    if (tid < 20) ws1[tid] = w1[tid];
    if (tid < 4) wb1[tid] = b1[tid];
    if (tid < 320) ws2[tid] = w2[tid];
    if (tid < 16) wb2[tid] = b2[tid];
    for (int q = tid; q < 520; q += 512) {
        int xi = t0 - 4 + q;
        xs[q] = (xi >= 0 && xi < 6000) ? x[(size_t)n * 6000 + xi] : 0.f;
    }
    __syncthreads();
    for (int p = tid; p < 516; p += 512) {
        int gp = t0 - 2 + p;
#pragma unroll
        for (int ch = 0; ch < 4; ++ch) {
            float a = wb1[ch];
#pragma unroll
            for (int j = 0; j < 5; ++j) a += ws1[ch * 5 + j] * xs[p + j];
            c1s[ch][p] = (gp >= 0 && gp < 6000) ? siluf(a) : 0.f;
        }
    }
    __syncthreads();
    int pos = t0 + tid;
    if (pos < 6000) {
#pragma unroll
        for (int oc = 0; oc < 16; ++oc) {
            float a = wb2[oc];
#pragma unroll
            for (int ic = 0; ic < 4; ++ic)
#pragma unroll
                for (int j = 0; j < 5; ++j)
                    a += ws2[(oc * 4 + ic) * 5 + j] * c1s[ic][tid + j];
            c2[((size_t)n * 16 + oc) * 6000 + pos] = siluf(a);
        }
    }
}

// ---------------- im2col for conv3 (K padded 304 -> 320) ----------------
__global__ void k_im2col(const float* __restrict__ c2, float* __restrict__ A3) {
    int flat = blockIdx.x * 256 + threadIdx.x; // < 38400*40
    int m = flat / 40, c8 = flat % 40;
    int t = m >> 5, n = m & 31;
    float v[8];
#pragma unroll
    for (int e = 0; e < 8; ++e) {
        int k = c8 * 8 + e;
        float r = 0.f;
        if (k < 304) {
            int ic = k / 19, j = k % 19;
            int p = t * 5 - 9 + j;
            if (p >= 0 && p < 6000) r = c2[((size_t)n * 16 + ic) * 6000 + p];
        }
        v[e] = r;
    }
    float4 a, b;
    a.x = v[0]; a.y = v[1]; a.z = v[2]; a.w = v[3];
    b.x = v[4]; b.y = v[5]; b.z = v[6]; b.w = v[7];
    *(float4*)&A3[(size_t)m * 320 + c8 * 8] = a;
    *(float4*)&A3[(size_t)m * 320 + c8 * 8 + 4] = b;
}

// ---------------- MFMA GEMM, f32 A (hi/lo split): C = act(A @ B^T + bias) ----------------
template <int ACT, typename OT>
__global__ __launch_bounds__(256, 2) void k_gemm(const float* __restrict__ A, const f16* __restrict__ B,
    const float* __restrict__ bias, OT* __restrict__ C, int K, int N) {
    const int tid = threadIdx.x;
    const int lane = tid & 63, wv = tid >> 6;
    const int wm = wv >> 1, wn = wv & 1;
    const int m0 = blockIdx.x * 128, n0 = blockIdx.y * 128;
    __shared__ __align__(16) f16 As[128 * 64];
    __shared__ __align__(16) f16 Al[128 * 64];
    __shared__ __align__(16) f16 Bs[128 * 64];
    f32x4 acc[4][4] = {};
    const int nk = K >> 6;
    for (int kb = 0; kb < nk; ++kb) {
#pragma unroll
        for (int i = 0; i < 4; ++i) {
            int cf = tid + i * 256;
            int row = cf >> 3, c = cf & 7;
            int sw = ((c ^ (row & 7)) << 3);
            *(f16x8*)&Bs[row * 64 + sw] = *(const f16x8*)&B[(size_t)(n0 + row) * K + kb * 64 + c * 8];
            float4 v0 = *(const float4*)&A[(size_t)(m0 + row) * K + kb * 64 + c * 8];
            float4 v1 = *(const float4*)&A[(size_t)(m0 + row) * K + kb * 64 + c * 8 + 4];
            float vv[8] = {v0.x, v0.y, v0.z, v0.w, v1.x, v1.y, v1.z, v1.w};
            f16x8 hi, lo;
#pragma unroll
            for (int e = 0; e < 8; ++e) {
                f16 h = (f16)vv[e];
                hi[e] = h;
                lo[e] = (f16)(vv[e] - (float)h);
            }
            *(f16x8*)&As[row * 64 + sw] = hi;
            *(f16x8*)&Al[row * 64 + sw] = lo;
        }
        __syncthreads();
#pragma unroll
        for (int kk = 0; kk < 2; ++kk) {
            f16x8 afh[4], afl[4], bf[4];
#pragma unroll
            for (int mi = 0; mi < 4; ++mi) {
                int row = wm * 64 + mi * 16 + (lane & 15);
                int c = kk * 4 + (lane >> 4);
                afh[mi] = *(const f16x8*)&As[row * 64 + ((c ^ (row & 7)) << 3)];
                afl[mi] = *(const f16x8*)&Al[row * 64 + ((c ^ (row & 7)) << 3)];
            }
#pragma unroll
            for (int ni = 0; ni < 4; ++ni) {
                int row = wn * 64 + ni * 16 + (lane & 15);
                int c = kk * 4 + (lane >> 4);
                bf[ni] = *(const f16x8*)&Bs[row * 64 + ((c ^ (row & 7)) << 3)];
            }
#pragma unroll
            for (int mi = 0; mi < 4; ++mi)
#pragma unroll
                for (int ni = 0; ni < 4; ++ni) {
                    acc[mi][ni] = __builtin_amdgcn_mfma_f32_16x16x32_f16(afh[mi], bf[ni], acc[mi][ni], 0, 0, 0);
                    acc[mi][ni] = __builtin_amdgcn_mfma_f32_16x16x32_f16(afl[mi], bf[ni], acc[mi][ni], 0, 0, 0);
                }
        }
        __syncthreads();
    }
#pragma unroll
    for (int mi = 0; mi < 4; ++mi) {
#pragma unroll
        for (int ni = 0; ni < 4; ++ni) {
            int gcol = n0 + wn * 64 + ni * 16 + (lane & 15);
            float bv = bias[gcol];
#pragma unroll
            for (int r = 0; r < 4; ++r) {
                int grow = m0 + wm * 64 + mi * 16 + (lane >> 4) * 4 + r;
                float v = acc[mi][ni][r] + bv;
                if (ACT == 1) v = v * (1.f / (1.f + __expf(-v)));
                else if (ACT == 2) v = 5.f - 10.f / (__expf(2.f * v) + 1.f);
                C[(size_t)grow * N + gcol] = (OT)v;
            }
        }
    }
}

// ---------------- MFMA GEMM, f16 A (single MFMA): C = act(A @ B^T + bias) ----------------
// For A = LSTM outputs X (|X|<1): f16 abs err <=5e-4, safe; halves MFMA work.
template <int ACT, typename OT>
__global__ __launch_bounds__(256, 2) void k_gemmH(const f16* __restrict__ A, const f16* __restrict__ B,
    const float* __restrict__ bias, OT* __restrict__ C, int K, int N) {
    const int tid = threadIdx.x;
    const int lane = tid & 63, wv = tid >> 6;
    const int wm = wv >> 1, wn = wv & 1;
    const int m0 = blockIdx.x * 128, n0 = blockIdx.y * 128;
    __shared__ __align__(16) f16 As[128 * 64];
    __shared__ __align__(16) f16 Bs[128 * 64];
    f32x4 acc[4][4] = {};
    const int nk = K >> 6;
    for (int kb = 0; kb < nk; ++kb) {
#pragma unroll
        for (int i = 0; i < 4; ++i) {
            int cf = tid + i * 256;
            int row = cf >> 3, c = cf & 7;
            int sw = ((c ^ (row & 7)) << 3);
            *(f16x8*)&As[row * 64 + sw] = *(const f16x8*)&A[(size_t)(m0 + row) * K + kb * 64 + c * 8];
            *(f16x8*)&Bs[row * 64 + sw] = *(const f16x8*)&B[(size_t)(n0 + row) * K + kb * 64 + c * 8];
        }
        __syncthreads();
#pragma unroll
        for (int kk = 0; kk < 2; ++kk) {
            f16x8 af[4], bf[4];
#pragma unroll
            for (int mi = 0; mi < 4; ++mi) {
                int row = wm * 64 + mi * 16 + (lane & 15);
                int c = kk * 4 + (lane >> 4);
                af[mi] = *(const f16x8*)&As[row * 64 + ((c ^ (row & 7)) << 3)];
            }
#pragma unroll
            for (int ni = 0; ni < 4; ++ni) {
                int row = wn * 64 + ni * 16 + (lane & 15);
                int c = kk * 4 + (lane >> 4);
                bf[ni] = *(const f16x8*)&Bs[row * 64 + ((c ^ (row & 7)) << 3)];
            }
#pragma unroll
            for (int mi = 0; mi < 4; ++mi)
#pragma unroll
                for (int ni = 0; ni < 4; ++ni)
                    acc[mi][ni] = __builtin_amdgcn_mfma_f32_16x16x32_f16(af[mi], bf[ni], acc[mi][ni], 0, 0, 0);
        }
        __syncthreads();
    }
#pragma unroll
    for (int mi = 0; mi < 4; ++mi) {
#pragma unroll
        for (int ni = 0; ni < 4; ++ni) {
            int gcol = n0 + wn * 64 + ni * 16 + (lane & 15);
            float bv = bias[gcol];
#pragma unroll
            for (int r = 0; r < 4; ++r) {
                int grow = m0 + wm * 64 + mi * 16 + (lane >> 4) * 4 + r;
                float v = acc[mi][ni][r] + bv;
                if (ACT == 1) v = v * (1.f / (1.f + __expf(-v)));
                else if (ACT == 2) v = 5.f - 10.f / (__expf(2.f * v) + 1.f);
                C[(size_t)grow * N + gcol] = (OT)v;
            }
        }
    }
}

// ---------------- LSTM recurrence: 32 teams (samples) x 8 WGs x 512 thr ----------------
// r12/r13 proven structure, byte-identical except Xout is f16 (|h|<1, safe).
__global__ __launch_bounds__(512, 2) void k_rec(const float* __restrict__ G,
    const float* __restrict__ whh, f16* __restrict__ Xout,
    u64* __restrict__ tup, int rev, unsigned tagbase) {
    const int tid = threadIdx.x;
    const int n = blockIdx.x & 31, w = blockIdx.x >> 5;
    const int g3 = tid >> 3, kq = tid & 7;
    __shared__ __align__(16) float hlds[416]; // 8 chunks x 52 (48 used): kq start
    __shared__ float gbuf[192];               // banks {0,20,8,28,16,4,24,12} - conflict-free
    float4 wreg[3][12];
#pragma unroll
    for (int r = 0; r < 3; ++r) {
        int lr = 3 * g3 + r;             // 0..191
        int gate = lr / 48, unit = lr % 48;
        const float* wp = whh + (size_t)(gate * HD + w * 48 + unit) * HD + kq * 48;
#pragma unroll
        for (int q = 0; q < 12; ++q) wreg[r][q] = *(const float4*)(wp + 4 * q);
    }
    if (tid < 416) hlds[tid] = 0.f;
    float cst = 0.f;
    // poller setup: absolute unit uu of a remote WG
    const bool isP = (tid >= 64 && tid < 400);
    int uu = 0; float* hq = nullptr;
    if (isP) {
        int p = tid - 64;                 // 0..335
        uu = (p < w * 48) ? p : (p + 48); // skip own WG's 48 units
        hq = &hlds[(uu / 48) * 52 + (uu % 48)];
    }
    float pg0 = 0.f, pg1 = 0.f, pg2 = 0.f, pg3 = 0.f;
    if (tid < 48) {
        int t0 = rev ? (T_LEN - 1) : 0;
        size_t gb = ((size_t)t0 * NB + n) * 1536 + w * 48 + tid;
        pg0 = G[gb]; pg1 = G[gb + 384]; pg2 = G[gb + 768]; pg3 = G[gb + 1152];
    }
    __syncthreads();

    for (int s = 0; s < T_LEN; ++s) {
        float q0 = 0.f, q1 = 0.f, q2 = 0.f, q3 = 0.f;
        const bool pref = (tid < 48) && (s + 1 < T_LEN);
        if (pref) {
            int tn = rev ? (T_LEN - 2 - s) : (s + 1);
            size_t gb = ((size_t)tn * NB + n) * 1536 + w * 48 + tid;
            q0 = G[gb]; q1 = G[gb + 384]; q2 = G[gb + 768]; q3 = G[gb + 1152];
        }
        // ---- matvec: 3 rows x 48 cols per thread ----
        float a0 = 0.f, a1 = 0.f, a2 = 0.f;
        const float4* hp = (const float4*)&hlds[kq * 52];
#pragma unroll
        for (int q = 0; q < 12; ++q) {
            float4 hv = hp[q];
            a0 = fmaf(wreg[0][q].x, hv.x, a0); a0 = fmaf(wreg[0][q].y, hv.y, a0);
            a0 = fmaf(wreg[0][q].z, hv.z, a0); a0 = fmaf(wreg[0][q].w, hv.w, a0);
            a1 = fmaf(wreg[1][q].x, hv.x, a1); a1 = fmaf(wreg[1][q].y, hv.y, a1);
            a1 = fmaf(wreg[1][q].z, hv.z, a1); a1 = fmaf(wreg[1][q].w, hv.w, a1);
            a2 = fmaf(wreg[2][q].x, hv.x, a2); a2 = fmaf(wreg[2][q].y, hv.y, a2);
            a2 = fmaf(wreg[2][q].z, hv.z, a2); a2 = fmaf(wreg[2][q].w, hv.w, a2);
        }
        a0 += __shfl_xor(a0, 1); a0 += __shfl_xor(a0, 2); a0 += __shfl_xor(a0, 4);
        a1 += __shfl_xor(a1, 1); a1 += __shfl_xor(a1, 2); a1 += __shfl_xor(a1, 4);
        a2 += __shfl_xor(a2, 1); a2 += __shfl_xor(a2, 2); a2 += __shfl_xor(a2, 4);
        if (kq == 0) {
            gbuf[3 * g3 + 0] = a0;
            gbuf[3 * g3 + 1] = a1;
            gbuf[3 * g3 + 2] = a2;
        }
        if (pref) {
            asm volatile("" : "+v"(q0), "+v"(q1), "+v"(q2), "+v"(q3));
        }
        __syncthreads(); // B1: gbuf ready; all hlds reads of step s done
        const int slot = s & 1;
        const unsigned tag = tagbase + (unsigned)s + 1u;
        if (tid < 48) {
            float iv = pg0 + gbuf[tid];
            float fv = pg1 + gbuf[48 + tid];
            float gv = pg2 + gbuf[96 + tid];
            float ov = pg3 + gbuf[144 + tid];
            cst = sigf(fv) * cst + sigf(iv) * tanhf_s(gv);
            float hv = sigf(ov) * tanhf_s(cst);
            int t = rev ? (T_LEN - 1 - s) : s;
            Xout[((size_t)t * NB + n) * HD + w * 48 + tid] = (f16)hv;
            hlds[w * 52 + tid] = hv; // own-WG hlds direct
            if (s + 1 < T_LEN)
                st_pkt_sys(&tup[((size_t)slot * NB + n) * 384 + w * 48 + tid],
                           ((u64)tag << 32) | (u64)__builtin_bit_cast(unsigned, hv));
        } else if (isP && s + 1 < T_LEN) {
            const u64* ta = &tup[((size_t)slot * NB + n) * 384 + uu];
            u64 v; int it = 0;
            do { v = ld_pkt_sys(ta); }
            while ((unsigned)(v >> 32) != tag && ++it < 2000000);
            hq[0] = __builtin_bit_cast(float, (unsigned)v);
        }
        if (pref) { pg0 = q0; pg1 = q1; pg2 = q2; pg3 = q3; }
        __syncthreads(); // B2: hlds for step s+1 complete
    }
}

// ---------------- CRF logZ ----------------
__global__ __launch_bounds__(256) void k_crf(const float* __restrict__ S,
    const int* __restrict__ idx, float* __restrict__ logz) {
    const int n = blockIdx.x, s = threadIdx.x;
    __shared__ float ash[256];
    __shared__ float bsh[256];
    int ix[5];
#pragma unroll
    for (int a = 0; a < 5; ++a) ix[a] = idx[s * 5 + a];
    float alpha = 0.f;
    float M[5];
#pragma unroll
    for (int a = 0; a < 5; ++a) M[a] = S[(size_t)n * 1280 + s * 5 + a];
    for (int t = 0; t < T_LEN; ++t) {
        ash[s] = alpha;
        __syncthreads();
        float av[5];
#pragma unroll
        for (int a = 0; a < 5; ++a) av[a] = ash[ix[a]] + M[a];
        if (t + 1 < T_LEN) {
#pragma unroll
            for (int a = 0; a < 5; ++a) M[a] = S[((size_t)(t + 1) * NB + n) * 1280 + s * 5 + a];
        }
        float mx = av[0];
#pragma unroll
        for (int a = 1; a < 5; ++a) mx = fmaxf(mx, av[a]);
        float sum = 0.f;
#pragma unroll
        for (int a = 0; a < 5; ++a) sum += __expf(av[a] - mx);
        alpha = mx + __logf(sum);
        __syncthreads();
    }
    ash[s] = alpha;
    __syncthreads();
    for (int off = 128; off > 0; off >>= 1) {
        if (s < off) ash[s] = fmaxf(ash[s], ash[s + off]);
        __syncthreads();
    }
    float mxv = ash[0];
    bsh[s] = __expf(alpha - mxv);
    __syncthreads();
    for (int off = 128; off > 0; off >>= 1) {
        if (s < off) bsh[s] += bsh[s + off];
        __syncthreads();
    }
    if (s == 0) logz[n] = mxv + __logf(bsh[0]);
}

// ---------------- subtract logz/T ----------------
__global__ void k_sub(float* __restrict__ out, const float* __restrict__ logz) {
    size_t i = (size_t)blockIdx.x * 256 + threadIdx.x; // one float4 each
    float4* p = (float4*)out + i;
    int nn = (int)((i / 320) & 31);
    float d = logz[nn] * (1.f / 1200.f);
    float4 v = *p;
    v.x -= d; v.y -= d; v.z -= d; v.w -= d;
    *p = v;
}

extern "C" void kernel_launch(void* const* d_in, const int* in_sizes, int n_in,
                              void* d_out, int out_size, void* d_ws, size_t ws_size,
                              hipStream_t stream) {
    (void)in_sizes; (void)n_in; (void)out_size; (void)ws_size;
    const float* x    = (const float*)d_in[0];
    const float* w1   = (const float*)d_in[1];
    const float* b1   = (const float*)d_in[2];
    const float* w2   = (const float*)d_in[3];
    const float* b2   = (const float*)d_in[4];
    const float* w3   = (const float*)d_in[5];
    const float* b3   = (const float*)d_in[6];
    const float* linw = (const float*)d_in[7];
    const float* linb = (const float*)d_in[8];
    const float* wih[5];
    const float* whh[5];
    const float* lb[5];
    for (int l = 0; l < 5; ++l) {
        wih[l] = (const float*)d_in[9 + 3 * l];
        whh[l] = (const float*)d_in[10 + 3 * l];
        lb[l]  = (const float*)d_in[11 + 3 * l];
    }
    const int* idx = (const int*)d_in[24];
    float* out = (float*)d_out;
    char* ws = (char*)d_ws;

    float* G32   = (float*)(ws + 0);            // 235,929,600
    float* A3f   = (float*)(ws + 0);            // 49,152,000 (overlaps G, used before)
    float* c2f   = (float*)(ws + 56000000);     // 12,288,000 (overlaps G, used before)
    f16* Xa16    = (f16*)(ws + 235929600);      // 29,491,200
    f16* Xb16    = (f16*)(ws + 294912000);      // 29,491,200
    f16* wihf    = (f16*)(ws + 353894400);      // 5,898,240
    f16* linwf   = (f16*)(ws + 359792640);      // 983,040
    f16* w3p     = (f16*)(ws + 360775680);      // 245,760 (dead after conv3 GEMM)
    u64* tup     = (u64*)(ws + 360775680);      // 196,608 (reuses w3p; memset below)
    float* logz  = (float*)(ws + 361021440);    // 128

    for (int l = 0; l < 5; ++l)
        k_cvt<<<dim3(2304), 256, 0, stream>>>(wih[l], wihf + (size_t)l * 589824, 589824);
    k_cvt<<<dim3(1920), 256, 0, stream>>>(linw, linwf, 491520);
    k_w3p<<<dim3(480), 256, 0, stream>>>(w3, w3p);
    k_conv12<<<dim3(12, 32), 512, 0, stream>>>(x, w1, b1, w2, b2, c2f);
    k_im2col<<<dim3(6000), 256, 0, stream>>>(c2f, A3f);
    k_gemm<1, f16><<<dim3(300, 3), 256, 0, stream>>>(A3f, w3p, b3, Xa16, 320, 384);
    // w3p dead from here; zero the packet region once per call (tags are unique
    // per layer within a call, so one memset suffices; re-runs on every replay).
    hipMemsetAsync((void*)tup, 0, 196608, stream);

    f16* Xcur = Xa16;
    f16* Xnxt = Xb16;
    for (int l = 0; l < 5; ++l) {
        k_gemmH<0, float><<<dim3(300, 12), 256, 0, stream>>>(Xcur, wihf + (size_t)l * 589824, lb[l], G32, 384, 1536);
        k_rec<<<dim3(256), 512, 0, stream>>>(G32, whh[l], Xnxt, tup,
                                             ((l & 1) == 0) ? 1 : 0, (unsigned)(l * 4096 + 1));
        f16* tmp = Xcur; Xcur = Xnxt; Xnxt = tmp;
    }
    k_gemmH<2, float><<<dim3(300, 10), 256, 0, stream>>>(Xcur, linwf, linb, out, 384, 1280);
    k_crf<<<dim3(32), 256, 0, stream>>>(out, idx, logz);
    k_sub<<<dim3(48000), 256, 0, stream>>>(out, logz);
}

// Round 19
// 11821.465 us; speedup vs baseline: 1.0820x; 1.0004x over previous
//
#include <hip/hip_runtime.h>
#include <cstdint>
#include <cstddef>

typedef _Float16 f16;
typedef _Float16 f16x8 __attribute__((ext_vector_type(8)));
typedef float f32x4 __attribute__((ext_vector_type(4)));
typedef unsigned long long u64;

#define T_LEN 1200
#define NB 32
#define HD 384

__device__ __forceinline__ float sigf(float x) { return 1.f / (1.f + __expf(-x)); }
__device__ __forceinline__ float tanhf_s(float x) {
    float ax = fabsf(x);
    float e = __expf(-2.f * ax);
    float r = (1.f - e) / (1.f + e);
    return copysignf(r, x);
}
__device__ __forceinline__ float siluf(float x) { return x * sigf(x); }

// Device-visible 8B single-copy-atomic packet {h, tag} (r6-proven wire).
__device__ __forceinline__ u64 ld_pkt_sys(const u64* p) {
    u64 r;
    asm volatile("global_load_dwordx2 %0, %1, off sc0 sc1\n\ts_waitcnt vmcnt(0)"
                 : "=v"(r) : "v"(p) : "memory");
    return r;
}
__device__ __forceinline__ void st_pkt_sys(u64* p, u64 v) {
    asm volatile("global_store_dwordx2 %0, %1, off sc0 sc1" :: "v"(p), "v"(v) : "memory");
}

// ---------------- small conversion kernels ----------------
__global__ void k_cvt(const float* __restrict__ src, f16* __restrict__ dst, int n) {
    int i = blockIdx.x * 256 + threadIdx.x;
    if (i < n) dst[i] = (f16)src[i];
}

__global__ void k_w3p(const float* __restrict__ w3, f16* __restrict__ dst) {
    int i = blockIdx.x * 256 + threadIdx.x; // 384*320
    if (i >= 384 * 320) return;
    int c = i / 320, k = i % 320;
    dst[i] = (f16)((k < 304) ? w3[c * 304 + k] : 0.f);
}

// ---------------- conv1 + conv2 fused (f32 out) ----------------
__global__ __launch_bounds__(512) void k_conv12(const float* __restrict__ x,
    const float* __restrict__ w1, const float* __restrict__ b1,
    const float* __restrict__ w2, const float* __restrict__ b2,
    float* __restrict__ c2) {
    const int tid = threadIdx.x;
    const int n = blockIdx.y;
    const int t0 = blockIdx.x * 512;
    __shared__ float xs[520];
    __shared__ float c1s[4][520];
    __shared__ float ws1[20], wb1[4], ws2[320], wb2[16];
    if (tid < 20) ws1[tid] = w1[tid];
    if (tid < 4) wb1[tid] = b1[tid];
    if (tid < 320) ws2[tid] = w2[tid];
    if (tid < 16) wb2[tid] = b2[tid];
    for (int q = tid; q < 520; q += 512) {
        int xi = t0 - 4 + q;
        xs[q] = (xi >= 0 && xi < 6000) ? x[(size_t)n * 6000 + xi] : 0.f;
    }
    __syncthreads();
    for (int p = tid; p < 516; p += 512) {
        int gp = t0 - 2 + p;
#pragma unroll
        for (int ch = 0; ch < 4; ++ch) {
            float a = wb1[ch];
#pragma unroll
            for (int j = 0; j < 5; ++j) a += ws1[ch * 5 + j] * xs[p + j];
            c1s[ch][p] = (gp >= 0 && gp < 6000) ? siluf(a) : 0.f;
        }
    }
    __syncthreads();
    int pos = t0 + tid;
    if (pos < 6000) {
#pragma unroll
        for (int oc = 0; oc < 16; ++oc) {
            float a = wb2[oc];
#pragma unroll
            for (int ic = 0; ic < 4; ++ic)
#pragma unroll
                for (int j = 0; j < 5; ++j)
                    a += ws2[(oc * 4 + ic) * 5 + j] * c1s[ic][tid + j];
            c2[((size_t)n * 16 + oc) * 6000 + pos] = siluf(a);
        }
    }
}

// ---------------- im2col for conv3 (K padded 304 -> 320) ----------------
__global__ void k_im2col(const float* __restrict__ c2, float* __restrict__ A3) {
    int flat = blockIdx.x * 256 + threadIdx.x; // < 38400*40
    int m = flat / 40, c8 = flat % 40;
    int t = m >> 5, n = m & 31;
    float v[8];
#pragma unroll
    for (int e = 0; e < 8; ++e) {
        int k = c8 * 8 + e;
        float r = 0.f;
        if (k < 304) {
            int ic = k / 19, j = k % 19;
            int p = t * 5 - 9 + j;
            if (p >= 0 && p < 6000) r = c2[((size_t)n * 16 + ic) * 6000 + p];
        }
        v[e] = r;
    }
    float4 a, b;
    a.x = v[0]; a.y = v[1]; a.z = v[2]; a.w = v[3];
    b.x = v[4]; b.y = v[5]; b.z = v[6]; b.w = v[7];
    *(float4*)&A3[(size_t)m * 320 + c8 * 8] = a;
    *(float4*)&A3[(size_t)m * 320 + c8 * 8 + 4] = b;
}

// ---------------- MFMA GEMM, f32 A (hi/lo split): C = act(A @ B^T + bias) ----------------
template <int ACT, typename OT>
__global__ __launch_bounds__(256, 2) void k_gemm(const float* __restrict__ A, const f16* __restrict__ B,
    const float* __restrict__ bias, OT* __restrict__ C, int K, int N) {
    const int tid = threadIdx.x;
    const int lane = tid & 63, wv = tid >> 6;
    const int wm = wv >> 1, wn = wv & 1;
    const int m0 = blockIdx.x * 128, n0 = blockIdx.y * 128;
    __shared__ __align__(16) f16 As[128 * 64];
    __shared__ __align__(16) f16 Al[128 * 64];
    __shared__ __align__(16) f16 Bs[128 * 64];
    f32x4 acc[4][4] = {};
    const int nk = K >> 6;
    for (int kb = 0; kb < nk; ++kb) {
#pragma unroll
        for (int i = 0; i < 4; ++i) {
            int cf = tid + i * 256;
            int row = cf >> 3, c = cf & 7;
            int sw = ((c ^ (row & 7)) << 3);
            *(f16x8*)&Bs[row * 64 + sw] = *(const f16x8*)&B[(size_t)(n0 + row) * K + kb * 64 + c * 8];
            float4 v0 = *(const float4*)&A[(size_t)(m0 + row) * K + kb * 64 + c * 8];
            float4 v1 = *(const float4*)&A[(size_t)(m0 + row) * K + kb * 64 + c * 8 + 4];
            float vv[8] = {v0.x, v0.y, v0.z, v0.w, v1.x, v1.y, v1.z, v1.w};
            f16x8 hi, lo;
#pragma unroll
            for (int e = 0; e < 8; ++e) {
                f16 h = (f16)vv[e];
                hi[e] = h;
                lo[e] = (f16)(vv[e] - (float)h);
            }
            *(f16x8*)&As[row * 64 + sw] = hi;
            *(f16x8*)&Al[row * 64 + sw] = lo;
        }
        __syncthreads();
#pragma unroll
        for (int kk = 0; kk < 2; ++kk) {
            f16x8 afh[4], afl[4], bf[4];
#pragma unroll
            for (int mi = 0; mi < 4; ++mi) {
                int row = wm * 64 + mi * 16 + (lane & 15);
                int c = kk * 4 + (lane >> 4);
                afh[mi] = *(const f16x8*)&As[row * 64 + ((c ^ (row & 7)) << 3)];
                afl[mi] = *(const f16x8*)&Al[row * 64 + ((c ^ (row & 7)) << 3)];
            }
#pragma unroll
            for (int ni = 0; ni < 4; ++ni) {
                int row = wn * 64 + ni * 16 + (lane & 15);
                int c = kk * 4 + (lane >> 4);
                bf[ni] = *(const f16x8*)&Bs[row * 64 + ((c ^ (row & 7)) << 3)];
            }
#pragma unroll
            for (int mi = 0; mi < 4; ++mi)
#pragma unroll
                for (int ni = 0; ni < 4; ++ni) {
                    acc[mi][ni] = __builtin_amdgcn_mfma_f32_16x16x32_f16(afh[mi], bf[ni], acc[mi][ni], 0, 0, 0);
                    acc[mi][ni] = __builtin_amdgcn_mfma_f32_16x16x32_f16(afl[mi], bf[ni], acc[mi][ni], 0, 0, 0);
                }
        }
        __syncthreads();
    }
#pragma unroll
    for (int mi = 0; mi < 4; ++mi) {
#pragma unroll
        for (int ni = 0; ni < 4; ++ni) {
            int gcol = n0 + wn * 64 + ni * 16 + (lane & 15);
            float bv = bias[gcol];
#pragma unroll
            for (int r = 0; r < 4; ++r) {
                int grow = m0 + wm * 64 + mi * 16 + (lane >> 4) * 4 + r;
                float v = acc[mi][ni][r] + bv;
                if (ACT == 1) v = v * (1.f / (1.f + __expf(-v)));
                else if (ACT == 2) v = 5.f - 10.f / (__expf(2.f * v) + 1.f);
                C[(size_t)grow * N + gcol] = (OT)v;
            }
        }
    }
}

// ---------------- MFMA GEMM, f16 A (single MFMA): C = act(A @ B^T + bias) ----------------
// For A = LSTM outputs X (|X|<1): f16 abs err <=5e-4, safe; halves MFMA work.
template <int ACT, typename OT>
__global__ __launch_bounds__(256, 2) void k_gemmH(const f16* __restrict__ A, const f16* __restrict__ B,
    const float* __restrict__ bias, OT* __restrict__ C, int K, int N) {
    const int tid = threadIdx.x;
    const int lane = tid & 63, wv = tid >> 6;
    const int wm = wv >> 1, wn = wv & 1;
    const int m0 = blockIdx.x * 128, n0 = blockIdx.y * 128;
    __shared__ __align__(16) f16 As[128 * 64];
    __shared__ __align__(16) f16 Bs[128 * 64];
    f32x4 acc[4][4] = {};
    const int nk = K >> 6;
    for (int kb = 0; kb < nk; ++kb) {
#pragma unroll
        for (int i = 0; i < 4; ++i) {
            int cf = tid + i * 256;
            int row = cf >> 3, c = cf & 7;
            int sw = ((c ^ (row & 7)) << 3);
            *(f16x8*)&As[row * 64 + sw] = *(const f16x8*)&A[(size_t)(m0 + row) * K + kb * 64 + c * 8];
            *(f16x8*)&Bs[row * 64 + sw] = *(const f16x8*)&B[(size_t)(n0 + row) * K + kb * 64 + c * 8];
        }
        __syncthreads();
#pragma unroll
        for (int kk = 0; kk < 2; ++kk) {
            f16x8 af[4], bf[4];
#pragma unroll
            for (int mi = 0; mi < 4; ++mi) {
                int row = wm * 64 + mi * 16 + (lane & 15);
                int c = kk * 4 + (lane >> 4);
                af[mi] = *(const f16x8*)&As[row * 64 + ((c ^ (row & 7)) << 3)];
            }
#pragma unroll
            for (int ni = 0; ni < 4; ++ni) {
                int row = wn * 64 + ni * 16 + (lane & 15);
                int c = kk * 4 + (lane >> 4);
                bf[ni] = *(const f16x8*)&Bs[row * 64 + ((c ^ (row & 7)) << 3)];
            }
#pragma unroll
            for (int mi = 0; mi < 4; ++mi)
#pragma unroll
                for (int ni = 0; ni < 4; ++ni)
                    acc[mi][ni] = __builtin_amdgcn_mfma_f32_16x16x32_f16(af[mi], bf[ni], acc[mi][ni], 0, 0, 0);
        }
        __syncthreads();
    }
#pragma unroll
    for (int mi = 0; mi < 4; ++mi) {
#pragma unroll
        for (int ni = 0; ni < 4; ++ni) {
            int gcol = n0 + wn * 64 + ni * 16 + (lane & 15);
            float bv = bias[gcol];
#pragma unroll
            for (int r = 0; r < 4; ++r) {
                int grow = m0 + wm * 64 + mi * 16 + (lane >> 4) * 4 + r;
                float v = acc[mi][ni][r] + bv;
                if (ACT == 1) v = v * (1.f / (1.f + __expf(-v)));
                else if (ACT == 2) v = 5.f - 10.f / (__expf(2.f * v) + 1.f);
                C[(size_t)grow * N + gcol] = (OT)v;
            }
        }
    }
}

// ---------------- LSTM recurrence: 32 teams (samples) x 8 WGs x 512 thr ----------------
// r12/r13 proven structure; producers (wave 0) and pollers (waves 1-6) live in
// DIFFERENT waves so the SIMD scheduler interleaves them (r18's lesson: putting
// them in one wave deadlocks under exec-mask serialization). Xout f16 (|h|<1).
__global__ __launch_bounds__(512, 2) void k_rec(const float* __restrict__ G,
    const float* __restrict__ whh, f16* __restrict__ Xout,
    u64* __restrict__ tup, int rev, unsigned tagbase) {
    const int tid = threadIdx.x;
    const int n = blockIdx.x & 31, w = blockIdx.x >> 5;
    const int g3 = tid >> 3, kq = tid & 7;
    __shared__ __align__(16) float hlds[416]; // 8 chunks x 52 (48 used): kq start
    __shared__ float gbuf[192];               // banks {0,20,8,28,16,4,24,12} - conflict-free
    float4 wreg[3][12];
#pragma unroll
    for (int r = 0; r < 3; ++r) {
        int lr = 3 * g3 + r;             // 0..191
        int gate = lr / 48, unit = lr % 48;
        const float* wp = whh + (size_t)(gate * HD + w * 48 + unit) * HD + kq * 48;
#pragma unroll
        for (int q = 0; q < 12; ++q) wreg[r][q] = *(const float4*)(wp + 4 * q);
    }
    if (tid < 416) hlds[tid] = 0.f;
    float cst = 0.f;
    // poller setup: absolute unit uu of a remote WG
    const bool isP = (tid >= 64 && tid < 400);
    int uu = 0; float* hq = nullptr;
    if (isP) {
        int p = tid - 64;                 // 0..335
        uu = (p < w * 48) ? p : (p + 48); // skip own WG's 48 units
        hq = &hlds[(uu / 48) * 52 + (uu % 48)];
    }
    float pg0 = 0.f, pg1 = 0.f, pg2 = 0.f, pg3 = 0.f;
    if (tid < 48) {
        int t0 = rev ? (T_LEN - 1) : 0;
        size_t gb = ((size_t)t0 * NB + n) * 1536 + w * 48 + tid;
        pg0 = G[gb]; pg1 = G[gb + 384]; pg2 = G[gb + 768]; pg3 = G[gb + 1152];
    }
    __syncthreads();

    for (int s = 0; s < T_LEN; ++s) {
        float q0 = 0.f, q1 = 0.f, q2 = 0.f, q3 = 0.f;
        const bool pref = (tid < 48) && (s + 1 < T_LEN);
        if (pref) {
            int tn = rev ? (T_LEN - 2 - s) : (s + 1);
            size_t gb = ((size_t)tn * NB + n) * 1536 + w * 48 + tid;
            q0 = G[gb]; q1 = G[gb + 384]; q2 = G[gb + 768]; q3 = G[gb + 1152];
        }
        // ---- matvec: 3 rows x 48 cols per thread ----
        float a0 = 0.f, a1 = 0.f, a2 = 0.f;
        const float4* hp = (const float4*)&hlds[kq * 52];
#pragma unroll
        for (int q = 0; q < 12; ++q) {
            float4 hv = hp[q];
            a0 = fmaf(wreg[0][q].x, hv.x, a0); a0 = fmaf(wreg[0][q].y, hv.y, a0);
            a0 = fmaf(wreg[0][q].z, hv.z, a0); a0 = fmaf(wreg[0][q].w, hv.w, a0);
            a1 = fmaf(wreg[1][q].x, hv.x, a1); a1 = fmaf(wreg[1][q].y, hv.y, a1);
            a1 = fmaf(wreg[1][q].z, hv.z, a1); a1 = fmaf(wreg[1][q].w, hv.w, a1);
            a2 = fmaf(wreg[2][q].x, hv.x, a2); a2 = fmaf(wreg[2][q].y, hv.y, a2);
            a2 = fmaf(wreg[2][q].z, hv.z, a2); a2 = fmaf(wreg[2][q].w, hv.w, a2);
        }
        a0 += __shfl_xor(a0, 1); a0 += __shfl_xor(a0, 2); a0 += __shfl_xor(a0, 4);
        a1 += __shfl_xor(a1, 1); a1 += __shfl_xor(a1, 2); a1 += __shfl_xor(a1, 4);
        a2 += __shfl_xor(a2, 1); a2 += __shfl_xor(a2, 2); a2 += __shfl_xor(a2, 4);
        if (kq == 0) {
            gbuf[3 * g3 + 0] = a0;
            gbuf[3 * g3 + 1] = a1;
            gbuf[3 * g3 + 2] = a2;
        }
        if (pref) {
            asm volatile("" : "+v"(q0), "+v"(q1), "+v"(q2), "+v"(q3));
        }
        __syncthreads(); // B1: gbuf ready; all hlds reads of step s done
        const int slot = s & 1;
        const unsigned tag = tagbase + (unsigned)s + 1u;
        if (tid < 48) {
            float iv = pg0 + gbuf[tid];
            float fv = pg1 + gbuf[48 + tid];
            float gv = pg2 + gbuf[96 + tid];
            float ov = pg3 + gbuf[144 + tid];
            cst = sigf(fv) * cst + sigf(iv) * tanhf_s(gv);
            float hv = sigf(ov) * tanhf_s(cst);
            int t = rev ? (T_LEN - 1 - s) : s;
            Xout[((size_t)t * NB + n) * HD + w * 48 + tid] = (f16)hv;
            hlds[w * 52 + tid] = hv; // own-WG hlds direct
            if (s + 1 < T_LEN)
                st_pkt_sys(&tup[((size_t)slot * NB + n) * 384 + w * 48 + tid],
                           ((u64)tag << 32) | (u64)__builtin_bit_cast(unsigned, hv));
        } else if (isP && s + 1 < T_LEN) {
            const u64* ta = &tup[((size_t)slot * NB + n) * 384 + uu];
            u64 v; int it = 0;
            do { v = ld_pkt_sys(ta); }
            while ((unsigned)(v >> 32) != tag && ++it < 2000000);
            hq[0] = __builtin_bit_cast(float, (unsigned)v);
        }
        if (pref) { pg0 = q0; pg1 = q1; pg2 = q2; pg3 = q3; }
        __syncthreads(); // B2: hlds for step s+1 complete
    }
}

// ---------------- CRF logZ ----------------
__global__ __launch_bounds__(256) void k_crf(const float* __restrict__ S,
    const int* __restrict__ idx, float* __restrict__ logz) {
    const int n = blockIdx.x, s = threadIdx.x;
    __shared__ float ash[256];
    __shared__ float bsh[256];
    int ix[5];
#pragma unroll
    for (int a = 0; a < 5; ++a) ix[a] = idx[s * 5 + a];
    float alpha = 0.f;
    float M[5];
#pragma unroll
    for (int a = 0; a < 5; ++a) M[a] = S[(size_t)n * 1280 + s * 5 + a];
    for (int t = 0; t < T_LEN; ++t) {
        ash[s] = alpha;
        __syncthreads();
        float av[5];
#pragma unroll
        for (int a = 0; a < 5; ++a) av[a] = ash[ix[a]] + M[a];
        if (t + 1 < T_LEN) {
#pragma unroll
            for (int a = 0; a < 5; ++a) M[a] = S[((size_t)(t + 1) * NB + n) * 1280 + s * 5 + a];
        }
        float mx = av[0];
#pragma unroll
        for (int a = 1; a < 5; ++a) mx = fmaxf(mx, av[a]);
        float sum = 0.f;
#pragma unroll
        for (int a = 0; a < 5; ++a) sum += __expf(av[a] - mx);
        alpha = mx + __logf(sum);
        __syncthreads();
    }
    ash[s] = alpha;
    __syncthreads();
    for (int off = 128; off > 0; off >>= 1) {
        if (s < off) ash[s] = fmaxf(ash[s], ash[s + off]);
        __syncthreads();
    }
    float mxv = ash[0];
    bsh[s] = __expf(alpha - mxv);
    __syncthreads();
    for (int off = 128; off > 0; off >>= 1) {
        if (s < off) bsh[s] += bsh[s + off];
        __syncthreads();
    }
    if (s == 0) logz[n] = mxv + __logf(bsh[0]);
}

// ---------------- subtract logz/T ----------------
__global__ void k_sub(float* __restrict__ out, const float* __restrict__ logz) {
    size_t i = (size_t)blockIdx.x * 256 + threadIdx.x; // one float4 each
    float4* p = (float4*)out + i;
    int nn = (int)((i / 320) & 31);
    float d = logz[nn] * (1.f / 1200.f);
    float4 v = *p;
    v.x -= d; v.y -= d; v.z -= d; v.w -= d;
    *p = v;
}

extern "C" void kernel_launch(void* const* d_in, const int* in_sizes, int n_in,
                              void* d_out, int out_size, void* d_ws, size_t ws_size,
                              hipStream_t stream) {
    (void)in_sizes; (void)n_in; (void)out_size; (void)ws_size;
    const float* x    = (const float*)d_in[0];
    const float* w1   = (const float*)d_in[1];
    const float* b1   = (const float*)d_in[2];
    const float* w2   = (const float*)d_in[3];
    const float* b2   = (const float*)d_in[4];
    const float* w3   = (const float*)d_in[5];
    const float* b3   = (const float*)d_in[6];
    const float* linw = (const float*)d_in[7];
    const float* linb = (const float*)d_in[8];
    const float* wih[5];
    const float* whh[5];
    const float* lb[5];
    for (int l = 0; l < 5; ++l) {
        wih[l] = (const float*)d_in[9 + 3 * l];
        whh[l] = (const float*)d_in[10 + 3 * l];
        lb[l]  = (const float*)d_in[11 + 3 * l];
    }
    const int* idx = (const int*)d_in[24];
    float* out = (float*)d_out;
    char* ws = (char*)d_ws;

    float* G32   = (float*)(ws + 0);            // 235,929,600
    float* A3f   = (float*)(ws + 0);            // 49,152,000 (overlaps G, used before)
    float* c2f   = (float*)(ws + 56000000);     // 12,288,000 (overlaps G, used before)
    f16* Xa16    = (f16*)(ws + 235929600);      // 29,491,200
    f16* Xb16    = (f16*)(ws + 294912000);      // 29,491,200
    f16* wihf    = (f16*)(ws + 353894400);      // 5,898,240
    f16* linwf   = (f16*)(ws + 359792640);      // 983,040
    f16* w3p     = (f16*)(ws + 360775680);      // 245,760 (dead after conv3 GEMM)
    u64* tup     = (u64*)(ws + 360775680);      // 196,608 (reuses w3p; memset below)
    float* logz  = (float*)(ws + 361021440);    // 128

    for (int l = 0; l < 5; ++l)
        k_cvt<<<dim3(2304), 256, 0, stream>>>(wih[l], wihf + (size_t)l * 589824, 589824);
    k_cvt<<<dim3(1920), 256, 0, stream>>>(linw, linwf, 491520);
    k_w3p<<<dim3(480), 256, 0, stream>>>(w3, w3p);
    k_conv12<<<dim3(12, 32), 512, 0, stream>>>(x, w1, b1, w2, b2, c2f);
    k_im2col<<<dim3(6000), 256, 0, stream>>>(c2f, A3f);
    k_gemm<1, f16><<<dim3(300, 3), 256, 0, stream>>>(A3f, w3p, b3, Xa16, 320, 384);
    // w3p dead from here; zero the packet region once per call (tags are unique
    // per layer within a call, so one memset suffices; re-runs on every replay).
    hipMemsetAsync((void*)tup, 0, 196608, stream);

    f16* Xcur = Xa16;
    f16* Xnxt = Xb16;
    for (int l = 0; l < 5; ++l) {
        k_gemmH<0, float><<<dim3(300, 12), 256, 0, stream>>>(Xcur, wihf + (size_t)l * 589824, lb[l], G32, 384, 1536);
        k_rec<<<dim3(256), 512, 0, stream>>>(G32, whh[l], Xnxt, tup,
                                             ((l & 1) == 0) ? 1 : 0, (unsigned)(l * 4096 + 1));
        f16* tmp = Xcur; Xcur = Xnxt; Xnxt = tmp;
    }
    k_gemmH<2, float><<<dim3(300, 10), 256, 0, stream>>>(Xcur, linwf, linb, out, 384, 1280);
    k_crf<<<dim3(32), 256, 0, stream>>>(out, idx, logz);
    k_sub<<<dim3(48000), 256, 0, stream>>>(out, logz);
}